// Round 2
// baseline (123.612 us; speedup 1.0000x reference)
//
#include <hip/hip_runtime.h>
#include <hip/hip_bf16.h>

#define NQ    12
#define DIM   4096
#define DEPTH 2
#define AMPS  64   // amplitudes per lane: DIM / 64 lanes

typedef __hip_bfloat16 bf16;

__device__ __forceinline__ float b2f(unsigned int u) {
  union { unsigned int i; float f; } v; v.i = u << 16; return v.f;
}

// Composite permutation of the 12 sequential ring CNOTs (i,(i+1)%12), i=0..11.
// Qubit q <-> bit (11-q). new_state[d] = old_state[ringperm(d)]  (= P^{-1}).
__device__ __forceinline__ int ringperm(int d) {
  int a = d ^ ((d & 1) << 11);
  return a ^ (a >> 1);
}

// Decide whether input buffers hold float32 (flag=1) or bf16 (flag=0).
// If float32: even-indexed ushorts are LOW mantissa halves of floats ->
// random exponents -> ~87% "insane" as bf16. If bf16: legit N(0,1), sane.
__global__ void detect_dtype(const unsigned short* __restrict__ xr,
                             int* __restrict__ flag) {
  if (threadIdx.x == 0 && blockIdx.x == 0) {
    int insane = 0;
    for (int i = 0; i < 16; ++i) {
      float v = b2f((unsigned int)xr[2 * i]);
      float a = fabsf(v);
      if (!(a <= 64.f) || (a != 0.f && a < 1e-8f)) ++insane;  // NaN fails a<=64
    }
    *flag = (insane >= 2) ? 1 : 0;
  }
}

__device__ __forceinline__ float ldv(const void* p, int i, bool f32) {
  if (f32) return ((const float*)p)[i];
  return b2f((unsigned int)((const unsigned short*)p)[i]);
}

// One wave (64 lanes) simulates one batch element. Amplitude index
// d = (j << 6) | lane: qubits 0..5 in j bits (in-register gates),
// qubits 6..11 in lane bits (shuffle gates).
__global__ __launch_bounds__(64) void qsim_kernel(
    const void* __restrict__ x,    // [B, 12]
    const void* __restrict__ w,    // [2, 12]
    const void* __restrict__ Wm,   // [2, 12]
    const void* __restrict__ bv,   // [2]
    void* __restrict__ out,        // [B, 2]
    const int* __restrict__ flag)
{
  __shared__ float st[DIM];                 // scratch for CNOT permutation
  __shared__ float cs[NQ], sn[NQ];          // initial RY(x) gates
  __shared__ float gc[DEPTH * NQ], gs[DEPTH * NQ];  // trainable RY gates

  const int lane = threadIdx.x;   // 0..63
  const int b = blockIdx.x;
  const bool f32 = (*flag != 0);

  if (lane < NQ) {
    float xv = 0.5f * ldv(x, b * NQ + lane, f32);
    cs[lane] = __cosf(xv);
    sn[lane] = __sinf(xv);
  }
  if (lane >= 32 && lane < 32 + DEPTH * NQ) {
    int i = lane - 32;
    float wv = 0.5f * ldv(w, i, f32);
    gc[i] = __cosf(wv);
    gs[i] = __sinf(wv);
  }
  __syncthreads();

  // ---- initial product state: factor = bit ? sin(x_q/2) : cos(x_q/2)
  // qubit q in 6..11 -> lane bit (11-q); qubit q in 0..5 -> j bit (5-q)
  float lp = 1.f;
#pragma unroll
  for (int q = 6; q < 12; ++q)
    lp *= ((lane >> (11 - q)) & 1) ? sn[q] : cs[q];

  float amp[AMPS];
#pragma unroll
  for (int j = 0; j < AMPS; ++j) {
    float a = lp;
    a *= (j & 32) ? sn[0] : cs[0];
    a *= (j & 16) ? sn[1] : cs[1];
    a *= (j & 8)  ? sn[2] : cs[2];
    a *= (j & 4)  ? sn[3] : cs[3];
    a *= (j & 2)  ? sn[4] : cs[4];
    a *= (j & 1)  ? sn[5] : cs[5];
    amp[j] = a;
  }

#pragma unroll 1
  for (int l = 0; l < DEPTH; ++l) {
    // ---- CNOT ring layer: one permutation pass through LDS
    __syncthreads();   // prev layer's st reads done
#pragma unroll
    for (int j = 0; j < AMPS; ++j) st[(j << 6) | lane] = amp[j];
    __syncthreads();
#pragma unroll
    for (int j = 0; j < AMPS; ++j) amp[j] = st[ringperm((j << 6) | lane)];

    // ---- RY gates, qubits 0..5: pairs inside the register file
#pragma unroll
    for (int q = 0; q < 6; ++q) {
      const int m = 1 << (5 - q);
      const float c = gc[l * NQ + q], s = gs[l * NQ + q];
#pragma unroll
      for (int j = 0; j < AMPS; ++j) {
        if (j & m) continue;
        float v0 = amp[j], v1 = amp[j | m];
        amp[j]     = c * v0 - s * v1;   // new|0> = c v0 - s v1
        amp[j | m] = s * v0 + c * v1;   // new|1> = s v0 + c v1
      }
    }
    // ---- RY gates, qubits 6..11: cross-lane via shfl_xor
#pragma unroll
    for (int q = 6; q < 12; ++q) {
      const int lm = 1 << (11 - q);
      const float c = gc[l * NQ + q], s = gs[l * NQ + q];
      const float se = (lane & lm) ? s : -s;  // hi: +s*v0 ; lo: -s*v1
#pragma unroll
      for (int j = 0; j < AMPS; ++j) {
        float other = __shfl_xor(amp[j], lm, 64);
        amp[j] = c * amp[j] + se * other;
      }
    }
  }

  // ---- measurement: <Z_q> = sum_d amp^2 * (1 - 2*bit_q(d))
  float P = 0.f;
  float z0 = 0.f, z1 = 0.f, z2 = 0.f, z3 = 0.f, z4 = 0.f, z5 = 0.f;
#pragma unroll
  for (int j = 0; j < AMPS; ++j) {
    float pr = amp[j] * amp[j];
    P += pr;
    z0 += (j & 32) ? -pr : pr;
    z1 += (j & 16) ? -pr : pr;
    z2 += (j & 8)  ? -pr : pr;
    z3 += (j & 4)  ? -pr : pr;
    z4 += (j & 2)  ? -pr : pr;
    z5 += (j & 1)  ? -pr : pr;
  }
  float z[NQ];
  z[0] = z0; z[1] = z1; z[2] = z2; z[3] = z3; z[4] = z4; z[5] = z5;
#pragma unroll
  for (int q = 6; q < 12; ++q)
    z[q] = ((lane >> (11 - q)) & 1) ? -P : P;

  // wave-wide butterfly sums (all lanes end with the total)
#pragma unroll
  for (int q = 0; q < NQ; ++q) {
#pragma unroll
    for (int off = 32; off; off >>= 1)
      z[q] += __shfl_xor(z[q], off, 64);
  }

  // ---- linear head: out[b][r] = b[r] + sum_q z[q] * W[r][q]
  if (lane < 2) {
    float o = ldv(bv, lane, f32);
#pragma unroll
    for (int q = 0; q < NQ; ++q)
      o += z[q] * ldv(Wm, lane * NQ + q, f32);
    if (f32) ((float*)out)[b * 2 + lane] = o;
    else     ((bf16*)out)[b * 2 + lane] = __float2bfloat16(o);
  }
}

extern "C" void kernel_launch(void* const* d_in, const int* in_sizes, int n_in,
                              void* d_out, int out_size, void* d_ws, size_t ws_size,
                              hipStream_t stream) {
  const void* x  = d_in[0];
  const void* w  = d_in[1];
  const void* Wm = d_in[2];
  const void* bv = d_in[3];
  int* flag = (int*)d_ws;
  // batch from out_size (dtype/units-independent): out is [B, 2]
  const int batch = out_size / 2;   // 4096
  detect_dtype<<<dim3(1), dim3(64), 0, stream>>>((const unsigned short*)x, flag);
  qsim_kernel<<<dim3(batch), dim3(64), 0, stream>>>(x, w, Wm, bv, d_out, flag);
}

// Round 7
// 96.052 us; speedup vs baseline: 1.2869x; 1.2869x over previous
//
#include <hip/hip_runtime.h>
#include <hip/hip_bf16.h>

#define NQ 12
typedef __hip_bfloat16 bf16;

__device__ __forceinline__ float b2f(unsigned int u) {
  union { unsigned int i; float f; } v; v.i = u << 16; return v.f;
}

// Dtype-adaptive scalar load (world: f32 — probe-verified on HW in R5/R6).
__device__ __forceinline__ float ldv(const void* p, int i, bool f32) {
  if (f32) return ((const float*)p)[i];
  return b2f((unsigned int)((const unsigned short*)p)[i]);
}

// Composite permutation of the 12 sequential ring CNOTs (i,(i+1)%12).
// Qubit q <-> bit (11-q). new_state[d] = old_state[ringperm(d)].
// HW-verified in Round 2 (passed).
__device__ __forceinline__ int ringperm(int d) {
  int a = d ^ ((d & 1) << 11);
  return a ^ (a >> 1);
}

// LDS bank swizzle (GF(2)-linear involution): transpose reads become <=2-way
// (free, m136) instead of 32-way.
__device__ __forceinline__ int swz(int p) { return p ^ ((p >> 6) & 31); }

// One wave per batch element; 64 amps/lane.
// Layout A: amp[j] = state[(j<<6)|lane]; Layout B: amp[j] = state[(lane<<6)|j].
// Per layer: LDS pass (CNOT perm + transpose A->B), register RY q6..11,
// LDS pass (transpose B->A), register RY q0..5. RYs commute -> exact.
// This structure produced outputs bit-identical to the R2-proven structure
// on HW (R5 vs R6 identical absmax) — equivalence empirically established.
__global__ __launch_bounds__(64) void qsim_kernel(
    const void* __restrict__ x,    // [B,12] f32
    const void* __restrict__ w,    // [2,12] f32
    const void* __restrict__ Wm,   // [2,12] f32
    const void* __restrict__ bv,   // [2]    f32
    void* __restrict__ out)        // [B,2]  f32 (proven by R2 pass on f32 path)
{
  __shared__ float st[4096];
  const int lane = threadIdx.x;
  const int b = blockIdx.x;

  // ---- inline dtype probe: low halves of random f32 are ~87% insane as
  // bf16; genuine bf16 data is sane. Robust (P(err) ~ 5e-13).
  bool f32;
  {
    const unsigned short* xu = (const unsigned short*)x;
    int insane = 0;
#pragma unroll
    for (int i = 0; i < 16; ++i) {
      float v = b2f((unsigned int)xu[2 * i]);
      float a = fabsf(v);
      if (!(a <= 64.f) || (a != 0.f && a < 1e-8f)) ++insane;  // NaN fails a<=64
    }
    f32 = (insane >= 2);
  }

  // ---- init product state, layout A ----
  float lp = 1.f;
#pragma unroll
  for (int q = 6; q < 12; ++q) {
    float h = 0.5f * ldv(x, b * NQ + q, f32);
    lp *= ((lane >> (11 - q)) & 1) ? __sinf(h) : __cosf(h);
  }
  float amp[64];
  {
    float h0 = 0.5f * ldv(x, b * NQ + 0, f32);
    amp[0] = lp * __cosf(h0);
    amp[1] = lp * __sinf(h0);
#pragma unroll
    for (int lvl = 1; lvl < 6; ++lvl) {
      float h = 0.5f * ldv(x, b * NQ + lvl, f32);
      float cc = __cosf(h), ss = __sinf(h);
#pragma unroll
      for (int i = (1 << lvl) - 1; i >= 0; --i) {
        float t = amp[i];
        amp[2 * i]     = t * cc;
        amp[2 * i + 1] = t * ss;
      }
    }
  }

#pragma unroll 1
  for (int l = 0; l < 2; ++l) {
    // ---- Pass 1: ring-CNOT perm + transpose, A -> B ----
    __syncthreads();
#pragma unroll
    for (int j = 0; j < 64; ++j) st[((j << 6) ^ (j & 31)) ^ lane] = amp[j];
    __syncthreads();
    {
      const int rb = swz(ringperm(lane << 6));
#pragma unroll
      for (int j = 0; j < 64; ++j) amp[j] = st[rb ^ swz(ringperm(j))];
    }

    // ---- RY gates, qubits 6..11 (register pairs in layout B) ----
#pragma unroll
    for (int q = 6; q < 12; ++q) {
      float h = 0.5f * ldv(w, l * NQ + q, f32);
      const float c = __cosf(h), s = __sinf(h);
      const int m = 1 << (11 - q);
#pragma unroll
      for (int j = 0; j < 64; ++j) {
        if (j & m) continue;
        float v0 = amp[j], v1 = amp[j | m];
        amp[j]     = fmaf(c, v0, -s * v1);
        amp[j | m] = fmaf(s, v0,  c * v1);
      }
    }

    // ---- Pass 2: pure transpose, B -> A ----
    __syncthreads();
    {
      const int wb = (lane << 6) ^ (lane & 31);
#pragma unroll
      for (int j = 0; j < 64; ++j) st[wb ^ j] = amp[j];
    }
    __syncthreads();
#pragma unroll
    for (int j = 0; j < 64; ++j) amp[j] = st[((j << 6) ^ (j & 31)) ^ lane];

    // ---- RY gates, qubits 0..5 (register pairs in layout A) ----
#pragma unroll
    for (int q = 0; q < 6; ++q) {
      float h = 0.5f * ldv(w, l * NQ + q, f32);
      const float c = __cosf(h), s = __sinf(h);
      const int m = 1 << (5 - q);
#pragma unroll
      for (int j = 0; j < 64; ++j) {
        if (j & m) continue;
        float v0 = amp[j], v1 = amp[j | m];
        amp[j]     = fmaf(c, v0, -s * v1);
        amp[j | m] = fmaf(s, v0,  c * v1);
      }
    }
  }

  // ---- measurement in layout A ----
  float P = 0.f, z0 = 0.f, z1 = 0.f, z2 = 0.f, z3 = 0.f, z4 = 0.f, z5 = 0.f;
#pragma unroll
  for (int j = 0; j < 64; ++j) {
    float pr = amp[j] * amp[j];
    P  += pr;
    z0 += (j & 32) ? -pr : pr;
    z1 += (j & 16) ? -pr : pr;
    z2 += (j & 8)  ? -pr : pr;
    z3 += (j & 4)  ? -pr : pr;
    z4 += (j & 2)  ? -pr : pr;
    z5 += (j & 1)  ? -pr : pr;
  }

  // ---- fused linear head: per-lane partials, then 2 butterflies ----
  float t0, t1;
#pragma unroll
  for (int r = 0; r < 2; ++r) {
    float acc = z0 * ldv(Wm, r * NQ + 0, f32) + z1 * ldv(Wm, r * NQ + 1, f32)
              + z2 * ldv(Wm, r * NQ + 2, f32) + z3 * ldv(Wm, r * NQ + 3, f32)
              + z4 * ldv(Wm, r * NQ + 4, f32) + z5 * ldv(Wm, r * NQ + 5, f32);
    float wsum = 0.f;
#pragma unroll
    for (int q = 6; q < 12; ++q) {
      float wv = ldv(Wm, r * NQ + q, f32);
      wsum += ((lane >> (11 - q)) & 1) ? -wv : wv;
    }
    acc = fmaf(P, wsum, acc);
    if (r == 0) t0 = acc; else t1 = acc;
  }
#pragma unroll
  for (int off = 32; off; off >>= 1) {
    t0 += __shfl_xor(t0, off, 64);
    t1 += __shfl_xor(t1, off, 64);
  }
  if (lane < 2) {
    float o = ((lane == 0) ? t0 : t1) + ldv(bv, lane, f32);
    // dtype-adaptive WRITE — this is what R2 did on its passing path and
    // what R5/R6 broke by hardcoding bf16 stores.
    if (f32) ((float*)out)[b * 2 + lane] = o;
    else     ((bf16*)out)[b * 2 + lane] = __float2bfloat16(o);
  }
}

extern "C" void kernel_launch(void* const* d_in, const int* in_sizes, int n_in,
                              void* d_out, int out_size, void* d_ws, size_t ws_size,
                              hipStream_t stream) {
  const void* x  = d_in[0];
  const void* w  = d_in[1];
  const void* Wm = d_in[2];
  const void* bv = d_in[3];
  const int batch = out_size / 2;   // out is [B, 2]
  qsim_kernel<<<dim3(batch), dim3(64), 0, stream>>>(x, w, Wm, bv, d_out);
}